// Round 7
// baseline (138.570 us; speedup 1.0000x reference)
//
#include <hip/hip_runtime.h>
#include <hip/hip_bf16.h>

// Problem constants
#define B_    8
#define Qn    16
#define S_    4096
#define Hh    32
#define KVH_  8
#define D_    128
#define G_    4
#define ROWS  64          // G_*Qn score rows per (b,kvh)
#define KT    32          // tokens per inner tile
#define NT_TOT (S_ / KT)  // 128 tiles across the sequence
#define THREADS 256
#define VTS   40          // vt row stride (shorts): 80B = 20 banks, 16B-aligned
#define PTS   40          // pt row stride (shorts)

typedef unsigned int u32;
typedef unsigned short u16;
typedef __attribute__((ext_vector_type(8))) short short8;   // 8 bf16 (4 VGPRs)
typedef __attribute__((ext_vector_type(4))) float f32x4;    // MFMA C/D

__device__ __forceinline__ u16 f2bf(float f){
  union{float f; u32 u;} t; t.f = f; u32 u = t.u;
  return (u16)((u + 0x7fffu + ((u >> 16) & 1u)) >> 16);   // RNE
}
__device__ __forceinline__ float bf2f(u16 h){
  union{u32 x; float f;} t; t.x = ((u32)h) << 16; return t.f;
}
// Quantize to signed nibble value held as bf16.
// scale = max(absmax/7,1e-8) => x*inv in [-7.001,7.001] => rint in [-7,7]:
// reference's [-8,7] clamp is dead; ints in [-7,7] have zero low-16 fp32
// mantissa bits => bf16 = plain truncation (exact).
__device__ __forceinline__ u16 qnib(float x, float inv){
  union{float f; u32 u;} t; t.f = rintf(x * inv);
  return (u16)(t.u >> 16);
}

// Pinned prefetch load: asm volatile, no "memory" clobber -> the compiler
// does not model it, so __syncthreads() does NOT drain it (counted-vmcnt
// pattern, T4/T14). Consumer side does s_waitcnt vmcnt(N) + sched_barrier(0).
__device__ __forceinline__ float4 gload4(const float* p){
  float4 r;
  asm volatile("global_load_dwordx4 %0, %1, off" : "=v"(r) : "v"(p));
  return r;
}
#define WAIT_VM4 do{ asm volatile("s_waitcnt vmcnt(4)" ::: "memory"); __builtin_amdgcn_sched_barrier(0); }while(0)
#define WAIT_VM0 do{ asm volatile("s_waitcnt vmcnt(0)" ::: "memory"); __builtin_amdgcn_sched_barrier(0); }while(0)

// attn_partial: grid (nchunk, KVH_, B_) x 256 threads, 4 blocks/CU.
// amdgpu_waves_per_eu(4,4): grid supplies exactly 4 waves/EU, so pin the
// allocator there (VGPR budget 128) instead of letting it spill for 8.
__global__ __launch_bounds__(THREADS)
__attribute__((amdgpu_waves_per_eu(4, 4)))
void attn_partial(const float* __restrict__ q, const float* __restrict__ k,
                  const float* __restrict__ v, float* __restrict__ part_o,
                  float* __restrict__ part_ml, int nchunk)
{
  __shared__ u16 kn[KT * D_];     // [tok][d]  quantized K, granule-swizzled 8 KB
  __shared__ u16 vt[D_ * VTS];    // [d][tok]  quantized V^T, padded rows   10 KB
  __shared__ u16 pt[ROWS * PTS];  // [qrow][tok] P~ = bf16(p*vscale)         5 KB
  __shared__ float kscale[KT];
  __shared__ float vscale[KT];

  const int chunk = blockIdx.x;
  const int kvh   = blockIdx.y;
  const int b     = blockIdx.z;
  const int tid   = threadIdx.x;
  const int lane  = tid & 63;
  const int w     = tid >> 6;                  // wave id == head group g
  const int l15   = lane & 15;
  const int l4    = lane >> 4;                 // 0..3
  const int t0    = (chunk * NT_TOT) / nchunk;
  const int t1    = ((chunk + 1) * NT_TOT) / nchunk;
  const float RS = 0.08838834764831844f;       // 1/sqrt(128)

  // staging: thread <-> token lt, dims {qd4 + m*32 + j : m 0..3, j 0..3}
  const int lt  = tid >> 3;                    // token 0..31
  const int qd4 = (tid & 7) * 4;

  // ---- Q fragments (hi/lo bf16 split) straight into registers ----
  short8 qhi[4], qlo[4];
  {
    const int h = kvh * G_ + w;
    const float* qp = q + (((size_t)(b * Qn + l15) * Hh) + h) * (size_t)D_ + (l4 * 8);
    #pragma unroll
    for (int kc = 0; kc < 4; ++kc){
      const float4 a = *(const float4*)(qp + kc * 32);
      const float4 c = *(const float4*)(qp + kc * 32 + 4);
      const float fv[8] = {a.x, a.y, a.z, a.w, c.x, c.y, c.z, c.w};
      #pragma unroll
      for (int i = 0; i < 8; ++i){
        const u16 hi = f2bf(fv[i]);
        qhi[kc][i] = (short)hi;
        qlo[kc][i] = (short)f2bf(fv[i] - bf2f(hi));
      }
    }
  }

  float m_i[4], l_i[4];
  f32x4 acc_o[8];                              // col d = df*16+l15, row = l4*4+reg
  #pragma unroll
  for (int r = 0; r < 4; ++r){ m_i[r] = -1e30f; l_i[r] = 0.f; }
  #pragma unroll
  for (int df = 0; df < 8; ++df) acc_o[df] = (f32x4)0.f;

  // global base for this thread's token slice
  const size_t kv_base = ((size_t)b * S_ + lt) * KVH_ * D_ + (size_t)kvh * D_ + qd4;

  // ---- prologue: pinned prefetch of tile t0 (K first, then V) ----
  float4 kreg[4], vreg[4];
  {
    const size_t gb = kv_base + (size_t)(t0 * KT) * KVH_ * D_;
    #pragma unroll
    for (int m = 0; m < 4; ++m) kreg[m] = gload4(k + gb + m * 32);
    #pragma unroll
    for (int m = 0; m < 4; ++m) vreg[m] = gload4(v + gb + m * 32);
  }

  for (int t = t0; t < t1; ++t){
    const int s0 = t * KT;

    // ---- K ready (V still flying): absmax + quant + stage ----
    WAIT_VM4;
    {
      float am = 0.f;
      #pragma unroll
      for (int m = 0; m < 4; ++m)
        am = fmaxf(am, fmaxf(fmaxf(fabsf(kreg[m].x), fabsf(kreg[m].y)),
                             fmaxf(fabsf(kreg[m].z), fabsf(kreg[m].w))));
      am = fmaxf(am, __shfl_xor(am, 1));
      am = fmaxf(am, __shfl_xor(am, 2));
      am = fmaxf(am, __shfl_xor(am, 4));
      const float sc = fmaxf(am * (1.f / 7.f), 1e-8f);
      if ((tid & 7) == 0) kscale[lt] = sc;
      const float inv = 1.f / sc;
      #pragma unroll
      for (int m = 0; m < 4; ++m){
        const int d0 = qd4 + m * 32;
        const int idx = lt * D_ + ((((d0 >> 3) ^ (lt & 7)) << 3) | (d0 & 7));
        *(ushort4*)&kn[idx] = make_ushort4(qnib(kreg[m].x, inv), qnib(kreg[m].y, inv),
                                           qnib(kreg[m].z, inv), qnib(kreg[m].w, inv));
      }
    }
    // ---- V ready: absmax + quant (transposed, padded rows) ----
    WAIT_VM0;
    {
      float am = 0.f;
      #pragma unroll
      for (int m = 0; m < 4; ++m)
        am = fmaxf(am, fmaxf(fmaxf(fabsf(vreg[m].x), fabsf(vreg[m].y)),
                             fmaxf(fabsf(vreg[m].z), fabsf(vreg[m].w))));
      am = fmaxf(am, __shfl_xor(am, 1));
      am = fmaxf(am, __shfl_xor(am, 2));
      am = fmaxf(am, __shfl_xor(am, 4));
      const float sc = fmaxf(am * (1.f / 7.f), 1e-8f);
      if ((tid & 7) == 0) vscale[lt] = sc;
      const float inv = 1.f / sc;
      #pragma unroll
      for (int m = 0; m < 4; ++m){
        const int d0 = qd4 + m * 32;
        vt[(d0 + 0) * VTS + lt] = qnib(vreg[m].x, inv);
        vt[(d0 + 1) * VTS + lt] = qnib(vreg[m].y, inv);
        vt[(d0 + 2) * VTS + lt] = qnib(vreg[m].z, inv);
        vt[(d0 + 3) * VTS + lt] = qnib(vreg[m].w, inv);
      }
    }

    // ---- issue pinned prefetch for tile t+1 (kreg/vreg now dead) ----
    // Stays in flight across the barrier and the whole MFMA/softmax phase.
    {
      const int sn = (s0 + KT <= S_ - KT) ? (s0 + KT) : (S_ - KT);
      const size_t gb = kv_base + (size_t)sn * KVH_ * D_;
      #pragma unroll
      for (int m = 0; m < 4; ++m) kreg[m] = gload4(k + gb + m * 32);
      #pragma unroll
      for (int m = 0; m < 4; ++m) vreg[m] = gload4(v + gb + m * 32);
    }
    __syncthreads();                           // staged tile visible to all waves

    // ---- QK^T via MFMA: wave computes 16 rows x 32 tokens ----
    f32x4 st[2];
    st[0] = (f32x4)0.f; st[1] = (f32x4)0.f;
    __builtin_amdgcn_s_setprio(1);
    #pragma unroll
    for (int kc = 0; kc < 4; ++kc){
      #pragma unroll
      for (int cf = 0; cf < 2; ++cf){
        const int tok = cf * 16 + l15;
        const int gr  = kc * 4 + l4;           // d-granule 0..15
        const short8 kf = *(const short8*)&kn[tok * D_ + ((gr ^ (tok & 7)) << 3)];
        st[cf] = __builtin_amdgcn_mfma_f32_16x16x32_bf16(qhi[kc], kf, st[cf], 0, 0, 0);
        st[cf] = __builtin_amdgcn_mfma_f32_16x16x32_bf16(qlo[kc], kf, st[cf], 0, 0, 0);
      }
    }
    __builtin_amdgcn_s_setprio(0);

    // ---- online softmax (rows = l4*4+reg, tokens over cf x l15) ----
    float sc2[2], vs2[2];
    #pragma unroll
    for (int cf = 0; cf < 2; ++cf){
      sc2[cf] = kscale[cf * 16 + l15] * RS;
      vs2[cf] = vscale[cf * 16 + l15];
    }
    const bool need_mask = (s0 + KT > S_ - Qn);      // only the last tile
    f32x4 facv;
    #pragma unroll
    for (int r = 0; r < 4; ++r){
      const int qi   = (l4 << 2) + r;          // 0..15 == query index
      float xr[2]; float rm;
      xr[0] = st[0][r] * sc2[0];
      xr[1] = st[1][r] * sc2[1];
      if (need_mask){
        const int slim = S_ - Qn + qi;
        if (s0 +      l15 > slim) xr[0] = -1e30f;
        if (s0 + 16 + l15 > slim) xr[1] = -1e30f;
      }
      rm = fmaxf(xr[0], xr[1]);
      rm = fmaxf(rm, __shfl_xor(rm, 1));
      rm = fmaxf(rm, __shfl_xor(rm, 2));
      rm = fmaxf(rm, __shfl_xor(rm, 4));
      rm = fmaxf(rm, __shfl_xor(rm, 8));
      const float mn  = fmaxf(m_i[r], rm);
      const float fac = __expf(m_i[r] - mn);
      const float p0 = __expf(xr[0] - mn);
      const float p1 = __expf(xr[1] - mn);
      float rs = p0 + p1;
      rs += __shfl_xor(rs, 1); rs += __shfl_xor(rs, 2);
      rs += __shfl_xor(rs, 4); rs += __shfl_xor(rs, 8);
      l_i[r] = l_i[r] * fac + rs;
      m_i[r] = mn;
      facv[r] = fac;
      const int qrow = (w << 4) + qi;
      pt[qrow * PTS +      l15] = f2bf(p0 * vs2[0]);   // fold vscale into P~
      pt[qrow * PTS + 16 + l15] = f2bf(p1 * vs2[1]);
    }
    #pragma unroll
    for (int df = 0; df < 8; ++df) acc_o[df] *= facv;

    // ---- PV via MFMA (pt rows are wave-private: no barrier needed) ----
    __builtin_amdgcn_s_setprio(1);
    {
      const int qrow = (w << 4) + l15;
      const short8 pf = *(const short8*)&pt[qrow * PTS + l4 * 8];
      #pragma unroll
      for (int df = 0; df < 8; ++df){
        const int d = df * 16 + l15;
        const short8 vf = *(const short8*)&vt[d * VTS + l4 * 8];
        acc_o[df] = __builtin_amdgcn_mfma_f32_16x16x32_bf16(pf, vf, acc_o[df], 0, 0, 0);
      }
    }
    __builtin_amdgcn_s_setprio(0);
    __syncthreads();                           // all reads done before next stage
  }

  // ---- write partials (unnormalized O, m, l) ----
  {
    const size_t base = (((size_t)b * KVH_ + kvh) * (size_t)nchunk + chunk) * ROWS;
    #pragma unroll
    for (int r = 0; r < 4; ++r){
      const int qrow = (w << 4) + (l4 << 2) + r;
      #pragma unroll
      for (int df = 0; df < 8; ++df)
        part_o[(base + qrow) * D_ + df * 16 + l15] = acc_o[df][r];
      if (l15 == 0){
        part_ml[(base + qrow) * 2 + 0] = m_i[r];
        part_ml[(base + qrow) * 2 + 1] = l_i[r];
      }
    }
  }
}

__global__ void attn_reduce(const float* __restrict__ part_o, const float* __restrict__ part_ml,
                            float* __restrict__ out, int nchunk)
{
  const int row = blockIdx.x;   // 0..63  (= g*16 + qi)
  const int kvh = blockIdx.y;
  const int b   = blockIdx.z;
  const int d   = threadIdx.x;  // 0..127
  const size_t base = ((size_t)b * KVH_ + kvh) * (size_t)nchunk;

  float M = -1e30f;
  for (int c = 0; c < nchunk; ++c)
    M = fmaxf(M, part_ml[((base + c) * ROWS + row) * 2 + 0]);
  float acc = 0.f, lt = 0.f;
  for (int c = 0; c < nchunk; ++c){
    const float m = part_ml[((base + c) * ROWS + row) * 2 + 0];
    const float l = part_ml[((base + c) * ROWS + row) * 2 + 1];
    const float w = __expf(m - M);
    lt += w * l;
    acc += w * part_o[((base + c) * ROWS + row) * D_ + d];
  }
  const int g = row >> 4, qi = row & 15;
  out[(((size_t)b * Qn + qi) * Hh + kvh * G_ + g) * (size_t)D_ + d] = acc / lt;
}

extern "C" void kernel_launch(void* const* d_in, const int* in_sizes, int n_in,
                              void* d_out, int out_size, void* d_ws, size_t ws_size,
                              hipStream_t stream)
{
  const float* q = (const float*)d_in[0];
  const float* k = (const float*)d_in[1];
  const float* v = (const float*)d_in[2];
  // d_in[3] = block_table: identity permutation round-trip; ECC encode/decode
  // with no injected errors is the identity on the nibble -> fake-quant only.
  float* out = (float*)d_out;

  // part_o: B*KVH*nchunk*ROWS*D floats (+ ml). nchunk=16 -> 1024 blocks = 4/CU.
  int nchunk = 16;
  while (nchunk > 1 &&
         ((size_t)B_ * KVH_ * nchunk * ROWS * (D_ + 2) * 4ull) > ws_size)
    nchunk >>= 1;

  float* part_o  = (float*)d_ws;
  float* part_ml = part_o + (size_t)B_ * KVH_ * nchunk * ROWS * D_;

  attn_partial<<<dim3(nchunk, KVH_, B_), THREADS, 0, stream>>>(q, k, v, part_o, part_ml, nchunk);
  attn_reduce<<<dim3(ROWS, KVH_, B_), 128, 0, stream>>>(part_o, part_ml, out, nchunk);
}

// Round 8
// 105.020 us; speedup vs baseline: 1.3195x; 1.3195x over previous
//
#include <hip/hip_runtime.h>
#include <hip/hip_bf16.h>

// Problem constants
#define B_    8
#define Qn    16
#define S_    4096
#define Hh    32
#define KVH_  8
#define D_    128
#define G_    4
#define ROWS  64          // G_*Qn score rows per (b,kvh)
#define KT    32          // tokens per inner tile
#define NT_TOT (S_ / KT)  // 128 tiles across the sequence
#define THREADS 256
#define VTS   40          // vt row stride (shorts): 80B, 16B-aligned reads

typedef unsigned int u32;
typedef unsigned short u16;
typedef __attribute__((ext_vector_type(8))) short short8;   // 8 bf16 (4 VGPRs)
typedef __attribute__((ext_vector_type(4))) float f32x4;    // MFMA C/D

__device__ __forceinline__ u16 f2bf(float f){
  union{float f; u32 u;} t; t.f = f; u32 u = t.u;
  return (u16)((u + 0x7fffu + ((u >> 16) & 1u)) >> 16);   // RNE
}
__device__ __forceinline__ float bf2f(u16 h){
  union{u32 x; float f;} t; t.x = ((u32)h) << 16; return t.f;
}
// Quantize to signed nibble value held as bf16.
// scale = max(absmax/7,1e-8) => x*inv in [-7.001,7.001] => rint in [-7,7]:
// reference's [-8,7] clamp is dead; ints in [-7,7] have zero low-16 fp32
// mantissa bits => bf16 = plain truncation (exact).
__device__ __forceinline__ u16 qnib(float x, float inv){
  union{float f; u32 u;} t; t.f = rintf(x * inv);
  return (u16)(t.u >> 16);
}

// attn_partial: grid (nchunk, KVH_, B_) x 256 threads.
// LDS 18.7 KB -> 8 blocks/CU; nchunk=32 -> 2048 blocks = 8/CU exactly.
// Swapped QK^T: st = mfma(K_frag, Q_frag) gives C[tok][qi] (col=qi=l15),
// so softmax reduces with 2 shfls and P~ transposes to the PV A-fragment
// in-register (8 shfls) -- no P LDS tile at all.
__global__ __launch_bounds__(THREADS)
void attn_partial(const float* __restrict__ q, const float* __restrict__ k,
                  const float* __restrict__ v, float* __restrict__ part_o,
                  float* __restrict__ part_ml, int nchunk)
{
  __shared__ u16 kn[KT * D_];     // [tok][d]  quantized K, granule-swizzled 8 KB
  __shared__ u16 vt[D_ * VTS];    // [d][tok]  quantized V^T, padded rows   10 KB
  __shared__ float kscale[KT];
  __shared__ float vscale[KT];

  const int chunk = blockIdx.x;
  const int kvh   = blockIdx.y;
  const int b     = blockIdx.z;
  const int tid   = threadIdx.x;
  const int lane  = tid & 63;
  const int w     = tid >> 6;                  // wave id == head group g
  const int l15   = lane & 15;
  const int l4    = lane >> 4;                 // 0..3
  const int t0    = (chunk * NT_TOT) / nchunk;
  const int t1    = ((chunk + 1) * NT_TOT) / nchunk;
  const float RS = 0.08838834764831844f;       // 1/sqrt(128)

  // staging: thread <-> token lt, dims {qd4 + m*32 + j : m 0..3, j 0..3}
  const int lt  = tid >> 3;                    // token 0..31
  const int qd4 = (tid & 7) * 4;

  // ---- Q fragments (hi/lo bf16 split) straight into registers ----
  // B-frag of swapped QK^T: lane holds Q[qi=l15][d = kc*32 + l4*8 + i]
  short8 qhi[4], qlo[4];
  {
    const int h = kvh * G_ + w;
    const float* qp = q + (((size_t)(b * Qn + l15) * Hh) + h) * (size_t)D_ + (l4 * 8);
    #pragma unroll
    for (int kc = 0; kc < 4; ++kc){
      const float4 a = *(const float4*)(qp + kc * 32);
      const float4 c = *(const float4*)(qp + kc * 32 + 4);
      const float fv[8] = {a.x, a.y, a.z, a.w, c.x, c.y, c.z, c.w};
      #pragma unroll
      for (int i = 0; i < 8; ++i){
        const u16 hi = f2bf(fv[i]);
        qhi[kc][i] = (short)hi;
        qlo[kc][i] = (short)f2bf(fv[i] - bf2f(hi));
      }
    }
  }

  // online-softmax state: per-lane, qi = l15 view (replicated over l4 groups)
  float m_i = -1e30f, l_i = 0.f;
  f32x4 acc_o[8];                              // O: col d = df*16+l15, row qi = l4*4+reg
  #pragma unroll
  for (int df = 0; df < 8; ++df) acc_o[df] = (f32x4)0.f;

  // global base for this thread's token slice
  const size_t kv_base = ((size_t)b * S_ + lt) * KVH_ * D_ + (size_t)kvh * D_ + qd4;

  for (int t = t0; t < t1; ++t){
    const int s0 = t * KT;
    const size_t gb = kv_base + (size_t)s0 * KVH_ * D_;

    // ---- load + quantize + stage K ----
    {
      float4 r4[4]; float am = 0.f;
      #pragma unroll
      for (int m = 0; m < 4; ++m){
        r4[m] = *(const float4*)(k + gb + m * 32);
        am = fmaxf(am, fmaxf(fmaxf(fabsf(r4[m].x), fabsf(r4[m].y)),
                             fmaxf(fabsf(r4[m].z), fabsf(r4[m].w))));
      }
      am = fmaxf(am, __shfl_xor(am, 1));
      am = fmaxf(am, __shfl_xor(am, 2));
      am = fmaxf(am, __shfl_xor(am, 4));
      const float sc = fmaxf(am * (1.f / 7.f), 1e-8f);
      if ((tid & 7) == 0) kscale[lt] = sc;
      const float inv = 1.f / sc;
      #pragma unroll
      for (int m = 0; m < 4; ++m){
        const int d0 = qd4 + m * 32;
        const int idx = lt * D_ + ((((d0 >> 3) ^ (lt & 7)) << 3) | (d0 & 7));
        *(ushort4*)&kn[idx] = make_ushort4(qnib(r4[m].x, inv), qnib(r4[m].y, inv),
                                           qnib(r4[m].z, inv), qnib(r4[m].w, inv));
      }
    }
    // ---- load + quantize + stage V (transposed, padded rows) ----
    {
      float4 r4[4]; float am = 0.f;
      #pragma unroll
      for (int m = 0; m < 4; ++m){
        r4[m] = *(const float4*)(v + gb + m * 32);
        am = fmaxf(am, fmaxf(fmaxf(fabsf(r4[m].x), fabsf(r4[m].y)),
                             fmaxf(fabsf(r4[m].z), fabsf(r4[m].w))));
      }
      am = fmaxf(am, __shfl_xor(am, 1));
      am = fmaxf(am, __shfl_xor(am, 2));
      am = fmaxf(am, __shfl_xor(am, 4));
      const float sc = fmaxf(am * (1.f / 7.f), 1e-8f);
      if ((tid & 7) == 0) vscale[lt] = sc;
      const float inv = 1.f / sc;
      #pragma unroll
      for (int m = 0; m < 4; ++m){
        const int d0 = qd4 + m * 32;
        vt[(d0 + 0) * VTS + lt] = qnib(r4[m].x, inv);
        vt[(d0 + 1) * VTS + lt] = qnib(r4[m].y, inv);
        vt[(d0 + 2) * VTS + lt] = qnib(r4[m].z, inv);
        vt[(d0 + 3) * VTS + lt] = qnib(r4[m].w, inv);
      }
    }
    __syncthreads();                           // staged tile visible to all waves

    // ---- QK^T (swapped): st[cf] = K * Q^T, C[tok=l4*4+r + 16cf][qi=l15] ----
    f32x4 st[2];
    st[0] = (f32x4)0.f; st[1] = (f32x4)0.f;
    __builtin_amdgcn_s_setprio(1);
    #pragma unroll
    for (int kc = 0; kc < 4; ++kc){
      #pragma unroll
      for (int cf = 0; cf < 2; ++cf){
        const int tok = cf * 16 + l15;
        const int gr  = kc * 4 + l4;           // d-granule 0..15
        const short8 kf = *(const short8*)&kn[tok * D_ + ((gr ^ (tok & 7)) << 3)];
        st[cf] = __builtin_amdgcn_mfma_f32_16x16x32_bf16(kf, qhi[kc], st[cf], 0, 0, 0);
        st[cf] = __builtin_amdgcn_mfma_f32_16x16x32_bf16(kf, qlo[kc], st[cf], 0, 0, 0);
      }
    }
    __builtin_amdgcn_s_setprio(0);

    // ---- online softmax in [tok][qi] layout ----
    // lane owns qi=l15; its 8 st values are tokens {cf*16 + l4*4 + r}.
    float ksr[2][4], vsv[2][4];
    #pragma unroll
    for (int cf = 0; cf < 2; ++cf){
      const float4 ks = *(const float4*)&kscale[cf * 16 + l4 * 4];
      const float4 vs = *(const float4*)&vscale[cf * 16 + l4 * 4];
      ksr[cf][0] = ks.x * RS; ksr[cf][1] = ks.y * RS;
      ksr[cf][2] = ks.z * RS; ksr[cf][3] = ks.w * RS;
      vsv[cf][0] = vs.x; vsv[cf][1] = vs.y; vsv[cf][2] = vs.z; vsv[cf][3] = vs.w;
    }
    const bool need_mask = (s0 + KT > S_ - Qn);      // only the last tile
    float x[2][4]; float rm = -1e30f;
    #pragma unroll
    for (int cf = 0; cf < 2; ++cf)
      #pragma unroll
      for (int r = 0; r < 4; ++r){
        float xx = st[cf][r] * ksr[cf][r];
        if (need_mask && (s0 + cf * 16 + l4 * 4 + r > S_ - Qn + l15)) xx = -1e30f;
        x[cf][r] = xx; rm = fmaxf(rm, xx);
      }
    rm = fmaxf(rm, __shfl_xor(rm, 16));
    rm = fmaxf(rm, __shfl_xor(rm, 32));
    const float mn  = fmaxf(m_i, rm);
    const float fac = __expf(m_i - mn);
    m_i = mn;
    float p[2][4]; float rs = 0.f;
    #pragma unroll
    for (int cf = 0; cf < 2; ++cf)
      #pragma unroll
      for (int r = 0; r < 4; ++r){
        p[cf][r] = __expf(x[cf][r] - mn);
        rs += p[cf][r];
      }
    rs += __shfl_xor(rs, 16);
    rs += __shfl_xor(rs, 32);
    l_i = l_i * fac + rs;

    // P~ = bf16(p * vscale[tok]) packed as u32 pairs (tokens 2rp, 2rp+1)
    u32 pk0[2], pk1[2];
    #pragma unroll
    for (int rp = 0; rp < 2; ++rp){
      pk0[rp] = (u32)f2bf(p[0][2*rp] * vsv[0][2*rp]) | ((u32)f2bf(p[0][2*rp+1] * vsv[0][2*rp+1]) << 16);
      pk1[rp] = (u32)f2bf(p[1][2*rp] * vsv[1][2*rp]) | ((u32)f2bf(p[1][2*rp+1] * vsv[1][2*rp+1]) << 16);
    }
    // transpose to PV A-frag: dest lane needs tokens 8*l4..8*l4+7 at its qi=l15.
    // sources: lanes l4' = 2*(l4&1)+{0,1}, cf = l4>>1.
    const int s0L = ((l4 & 1) * 2) * 16 + l15;
    const int s1L = s0L + 16;
    const u32 a00 = __shfl((int)pk0[0], s0L), a01 = __shfl((int)pk0[1], s0L);
    const u32 a02 = __shfl((int)pk0[0], s1L), a03 = __shfl((int)pk0[1], s1L);
    const u32 a10 = __shfl((int)pk1[0], s0L), a11 = __shfl((int)pk1[1], s0L);
    const u32 a12 = __shfl((int)pk1[0], s1L), a13 = __shfl((int)pk1[1], s1L);
    const bool hi = (l4 >= 2);
    union { uint4 u; short8 s; } pfu;
    pfu.u = make_uint4(hi ? a10 : a00, hi ? a11 : a01,
                       hi ? a12 : a02, hi ? a13 : a03);
    const short8 pf = pfu.s;

    // rescale acc_o: fac lives per qi=l15; acc rows are qi = l4*4+reg
    f32x4 facv;
    #pragma unroll
    for (int r = 0; r < 4; ++r) facv[r] = __shfl(fac, l4 * 4 + r);
    #pragma unroll
    for (int df = 0; df < 8; ++df) acc_o[df] *= facv;

    // ---- PV via MFMA: A = P~ (16 qi x 32 tok, in-register), B = V^T tile ----
    __builtin_amdgcn_s_setprio(1);
    #pragma unroll
    for (int df = 0; df < 8; ++df){
      const int d = df * 16 + l15;
      const short8 vf = *(const short8*)&vt[d * VTS + l4 * 8];
      acc_o[df] = __builtin_amdgcn_mfma_f32_16x16x32_bf16(pf, vf, acc_o[df], 0, 0, 0);
    }
    __builtin_amdgcn_s_setprio(0);
    __syncthreads();                           // all reads done before next stage
  }

  // ---- write partials (unnormalized O, m, l) ----
  {
    const size_t base = (((size_t)b * KVH_ + kvh) * (size_t)nchunk + chunk) * ROWS;
    #pragma unroll
    for (int r = 0; r < 4; ++r){
      const int qrow = (w << 4) + (l4 << 2) + r;
      #pragma unroll
      for (int df = 0; df < 8; ++df)
        part_o[(base + qrow) * D_ + df * 16 + l15] = acc_o[df][r];
    }
    if (l4 == 0){                              // lanes 0..15 hold qi=l15 state
      part_ml[(base + (w << 4) + l15) * 2 + 0] = m_i;
      part_ml[(base + (w << 4) + l15) * 2 + 1] = l_i;
    }
  }
}

__global__ void attn_reduce(const float* __restrict__ part_o, const float* __restrict__ part_ml,
                            float* __restrict__ out, int nchunk)
{
  const int row = blockIdx.x;   // 0..63  (= g*16 + qi)
  const int kvh = blockIdx.y;
  const int b   = blockIdx.z;
  const int d   = threadIdx.x;  // 0..127
  const size_t base = ((size_t)b * KVH_ + kvh) * (size_t)nchunk;

  float M = -1e30f;
  for (int c = 0; c < nchunk; ++c)
    M = fmaxf(M, part_ml[((base + c) * ROWS + row) * 2 + 0]);
  float acc = 0.f, lt = 0.f;
  #pragma unroll 4
  for (int c = 0; c < nchunk; ++c){
    const float m = part_ml[((base + c) * ROWS + row) * 2 + 0];
    const float l = part_ml[((base + c) * ROWS + row) * 2 + 1];
    const float w = __expf(m - M);
    lt += w * l;
    acc += w * part_o[((base + c) * ROWS + row) * D_ + d];
  }
  const int g = row >> 4, qi = row & 15;
  out[(((size_t)b * Qn + qi) * Hh + kvh * G_ + g) * (size_t)D_ + d] = acc / lt;
}

extern "C" void kernel_launch(void* const* d_in, const int* in_sizes, int n_in,
                              void* d_out, int out_size, void* d_ws, size_t ws_size,
                              hipStream_t stream)
{
  const float* q = (const float*)d_in[0];
  const float* k = (const float*)d_in[1];
  const float* v = (const float*)d_in[2];
  // d_in[3] = block_table: identity permutation round-trip; ECC encode/decode
  // with no injected errors is the identity on the nibble -> fake-quant only.
  float* out = (float*)d_out;

  // nchunk=32 -> 2048 blocks = 8 blocks/CU (LDS 18.7 KB) = 100% occupancy cap.
  int nchunk = 32;
  while (nchunk > 4 &&
         ((size_t)B_ * KVH_ * nchunk * ROWS * (D_ + 2) * 4ull) > ws_size)
    nchunk >>= 1;

  float* part_o  = (float*)d_ws;
  float* part_ml = part_o + (size_t)B_ * KVH_ * nchunk * ROWS * D_;

  attn_partial<<<dim3(nchunk, KVH_, B_), THREADS, 0, stream>>>(q, k, v, part_o, part_ml, nchunk);
  attn_reduce<<<dim3(ROWS, KVH_, B_), 128, 0, stream>>>(part_o, part_ml, out, nchunk);
}

// Round 9
// 79.532 us; speedup vs baseline: 1.7423x; 1.3205x over previous
//
#include <hip/hip_runtime.h>
#include <hip/hip_bf16.h>

// Problem constants
#define B_    8
#define Qn    16
#define S_    4096
#define Hh    32
#define KVH_  8
#define D_    128
#define G_    4
#define ROWS  64          // G_*Qn score rows per (b,kvh)
#define KT    32          // tokens per inner tile
#define NT_TOT (S_ / KT)  // 128 tiles across the sequence
#define NCHUNK 8          // 512 blocks = 2 blocks/CU (LDS-limited), zero tail
#define THREADS 256
#define VTS   40          // vt row stride (shorts): 80B, 16B-aligned reads

typedef unsigned int u32;
typedef unsigned short u16;
typedef __attribute__((ext_vector_type(8))) short short8;   // 8 bf16 (4 VGPRs)
typedef __attribute__((ext_vector_type(4))) float f32x4;    // MFMA C/D

__device__ __forceinline__ u16 f2bf(float f){
  union{float f; u32 u;} t; t.f = f; u32 u = t.u;
  return (u16)((u + 0x7fffu + ((u >> 16) & 1u)) >> 16);   // RNE
}
__device__ __forceinline__ float bf2f(u16 h){
  union{u32 x; float f;} t; t.x = ((u32)h) << 16; return t.f;
}
// Quantize to signed nibble value held as bf16 (ints in [-7,7] exact, see R2).
__device__ __forceinline__ u16 qnib(float x, float inv){
  union{float f; u32 u;} t; t.f = rintf(x * inv);
  return (u16)(t.u >> 16);
}

// Async global->LDS DMA: no result register, tracked by vmcnt, and NOT drained
// by raw s_barrier. LDS dest = wave-uniform base + lane*16 (linear).
__device__ __forceinline__ void gll16(const float* g, const float* lds){
  __builtin_amdgcn_global_load_lds((const __attribute__((address_space(1))) void*)g,
                                   (__attribute__((address_space(3))) void*)lds,
                                   16, 0, 0);
}

// attn_partial: grid (NCHUNK, KVH_, B_) x 256 threads, 2 blocks/CU.
// Pipeline: issue gll(t+1) -> vmcnt(8) -> bar -> build K frags + stage V from
// raw[t&1] -> bar -> MFMA/softmax/PV. t+1's 8 loads/wave stay in flight across
// both barriers and all compute (counted-vmcnt, T3/T4).
// Raw tiles are source-XOR-swizzled (16B granule ^ (tok&7)) so fragment reads
// are bank-spread; gll writes linearly so the permutation is applied to the
// GLOBAL source address at stage time and to the LDS address at read time.
__global__ __launch_bounds__(THREADS)
__attribute__((amdgpu_waves_per_eu(2, 2)))
void attn_partial(const float* __restrict__ q, const float* __restrict__ k,
                  const float* __restrict__ v, float* __restrict__ part_o,
                  float* __restrict__ part_ml)
{
  __shared__ float rawK[2][KT * D_];   // 32 KB (double-buffered raw f32)
  __shared__ float rawV[2][KT * D_];   // 32 KB
  __shared__ u16   vt[D_ * VTS];       // 10 KB quantized V^T (padded rows)
  __shared__ float vscale[KT];

  const int chunk = blockIdx.x;
  const int kvh   = blockIdx.y;
  const int b     = blockIdx.z;
  const int tid   = threadIdx.x;
  const int lane  = tid & 63;
  const int w     = tid >> 6;                  // wave id == head group g
  const int l15   = lane & 15;
  const int l4    = lane >> 4;                 // 0..3
  const int t0    = (chunk * NT_TOT) / NCHUNK;
  const int t1    = ((chunk + 1) * NT_TOT) / NCHUNK;
  const float RS = 0.08838834764831844f;       // 1/sqrt(128)

  // V staging assignment: thread <-> token lt, granules c = (tid&7)+8m
  const int lt  = tid >> 3;                    // token 0..31
  const int qd4 = (tid & 7) * 4;

  // ---- Q fragments (hi/lo bf16 split) straight into registers ----
  short8 qhi[4], qlo[4];
  {
    const int h = kvh * G_ + w;
    const float* qp = q + (((size_t)(b * Qn + l15) * Hh) + h) * (size_t)D_ + (l4 * 8);
    #pragma unroll
    for (int kc = 0; kc < 4; ++kc){
      const float4 a = *(const float4*)(qp + kc * 32);
      const float4 c = *(const float4*)(qp + kc * 32 + 4);
      const float fv[8] = {a.x, a.y, a.z, a.w, c.x, c.y, c.z, c.w};
      #pragma unroll
      for (int i = 0; i < 8; ++i){
        const u16 hi = f2bf(fv[i]);
        qhi[kc][i] = (short)hi;
        qlo[kc][i] = (short)f2bf(fv[i] - bf2f(hi));
      }
    }
  }

  float m_i = -1e30f, l_i = 0.f;               // per-lane, qi = l15 view
  f32x4 acc_o[8];                              // O: col d = df*16+l15, row qi = l4*4+reg
  #pragma unroll
  for (int df = 0; df < 8; ++df) acc_o[df] = (f32x4)0.f;

  // gll mapping: issue j covers physical granules (w*4+j)*64 + lane.
  // phys granule (tok_p, cp) holds global granule (tok_p, cp ^ (tok_p&7)).
  const int lhi = lane >> 5, cp = lane & 31;
  int goff[4];
  #pragma unroll
  for (int j = 0; j < 4; ++j){
    const int tokp = (w * 4 + j) * 2 + lhi;
    goff[j] = tokp * (KVH_ * D_) + ((cp ^ (tokp & 7)) << 2);
  }
  const size_t tb0 = ((size_t)b * S_) * KVH_ * D_ + (size_t)kvh * D_;

  // ---- prologue: issue async staging of tile t0 ----
  {
    const size_t base = tb0 + (size_t)(t0 * KT) * KVH_ * D_;
    #pragma unroll
    for (int j = 0; j < 4; ++j) gll16(k + base + goff[j], &rawK[t0 & 1][(w * 4 + j) * 256]);
    #pragma unroll
    for (int j = 0; j < 4; ++j) gll16(v + base + goff[j], &rawV[t0 & 1][(w * 4 + j) * 256]);
  }

  for (int t = t0; t < t1; ++t){
    const int s0  = t * KT;
    const int buf = t & 1;

    // ---- issue async staging for t+1 (clamped; stays in flight all iter) ----
    {
      const int sn = (s0 + KT <= S_ - KT) ? (s0 + KT) : (S_ - KT);
      const size_t base = tb0 + (size_t)sn * KVH_ * D_;
      #pragma unroll
      for (int j = 0; j < 4; ++j) gll16(k + base + goff[j], &rawK[buf ^ 1][(w * 4 + j) * 256]);
      #pragma unroll
      for (int j = 0; j < 4; ++j) gll16(v + base + goff[j], &rawV[buf ^ 1][(w * 4 + j) * 256]);
    }
    asm volatile("s_waitcnt vmcnt(8)" ::: "memory");   // t arrived; t+1 flying
    __builtin_amdgcn_sched_barrier(0);
    __builtin_amdgcn_s_barrier();                      // all waves' t-data visible
    __builtin_amdgcn_sched_barrier(0);

    // ---- K fragments from raw LDS: absmax (2 shfls) + in-reg quant ----
    float sc_cf[2]; short8 kfq[2][4];
    #pragma unroll
    for (int cf = 0; cf < 2; ++cf){
      const int tok = cf * 16 + l15;
      const int sw  = tok & 7;
      float4 a4[4], b4[4];
      #pragma unroll
      for (int kc = 0; kc < 4; ++kc){
        const int c0 = kc * 8 + l4 * 2;
        a4[kc] = *(const float4*)&rawK[buf][tok * D_ + (((c0    ) ^ sw) << 2)];
        b4[kc] = *(const float4*)&rawK[buf][tok * D_ + (((c0 + 1) ^ sw) << 2)];
      }
      float am = 0.f;
      #pragma unroll
      for (int kc = 0; kc < 4; ++kc){
        am = fmaxf(am, fmaxf(fmaxf(fabsf(a4[kc].x), fabsf(a4[kc].y)),
                             fmaxf(fabsf(a4[kc].z), fabsf(a4[kc].w))));
        am = fmaxf(am, fmaxf(fmaxf(fabsf(b4[kc].x), fabsf(b4[kc].y)),
                             fmaxf(fabsf(b4[kc].z), fabsf(b4[kc].w))));
      }
      am = fmaxf(am, __shfl_xor(am, 16));
      am = fmaxf(am, __shfl_xor(am, 32));
      const float sc = fmaxf(am * (1.f / 7.f), 1e-8f);
      sc_cf[cf] = sc;
      const float inv = 1.f / sc;
      #pragma unroll
      for (int kc = 0; kc < 4; ++kc){
        short8 f;
        f[0] = (short)qnib(a4[kc].x, inv); f[1] = (short)qnib(a4[kc].y, inv);
        f[2] = (short)qnib(a4[kc].z, inv); f[3] = (short)qnib(a4[kc].w, inv);
        f[4] = (short)qnib(b4[kc].x, inv); f[5] = (short)qnib(b4[kc].y, inv);
        f[6] = (short)qnib(b4[kc].z, inv); f[7] = (short)qnib(b4[kc].w, inv);
        kfq[cf][kc] = f;
      }
    }

    // ---- V stage from raw LDS: absmax + quant + transposed vt write ----
    {
      const int swv = lt & 7;
      float4 r4[4];
      #pragma unroll
      for (int m = 0; m < 4; ++m){
        const int c = (tid & 7) + 8 * m;
        r4[m] = *(const float4*)&rawV[buf][lt * D_ + ((c ^ swv) << 2)];
      }
      float am = 0.f;
      #pragma unroll
      for (int m = 0; m < 4; ++m)
        am = fmaxf(am, fmaxf(fmaxf(fabsf(r4[m].x), fabsf(r4[m].y)),
                             fmaxf(fabsf(r4[m].z), fabsf(r4[m].w))));
      am = fmaxf(am, __shfl_xor(am, 1));
      am = fmaxf(am, __shfl_xor(am, 2));
      am = fmaxf(am, __shfl_xor(am, 4));
      const float sc = fmaxf(am * (1.f / 7.f), 1e-8f);
      if ((tid & 7) == 0) vscale[lt] = sc;
      const float inv = 1.f / sc;
      #pragma unroll
      for (int m = 0; m < 4; ++m){
        const int d0 = qd4 + m * 32;
        vt[(d0 + 0) * VTS + lt] = qnib(r4[m].x, inv);
        vt[(d0 + 1) * VTS + lt] = qnib(r4[m].y, inv);
        vt[(d0 + 2) * VTS + lt] = qnib(r4[m].z, inv);
        vt[(d0 + 3) * VTS + lt] = qnib(r4[m].w, inv);
      }
    }
    asm volatile("s_waitcnt lgkmcnt(0)" ::: "memory"); // vt + vscale written
    __builtin_amdgcn_sched_barrier(0);
    __builtin_amdgcn_s_barrier();
    __builtin_amdgcn_sched_barrier(0);

    // ---- QK^T (swapped): st[cf] C[tok=l4*4+r+16cf][qi=l15], K frags in-reg ----
    f32x4 st[2];
    st[0] = (f32x4)0.f; st[1] = (f32x4)0.f;
    __builtin_amdgcn_s_setprio(1);
    #pragma unroll
    for (int kc = 0; kc < 4; ++kc){
      #pragma unroll
      for (int cf = 0; cf < 2; ++cf){
        st[cf] = __builtin_amdgcn_mfma_f32_16x16x32_bf16(kfq[cf][kc], qhi[kc], st[cf], 0, 0, 0);
        st[cf] = __builtin_amdgcn_mfma_f32_16x16x32_bf16(kfq[cf][kc], qlo[kc], st[cf], 0, 0, 0);
      }
    }
    __builtin_amdgcn_s_setprio(0);

    // ---- online softmax in [tok][qi] layout (R7-verified core) ----
    float ksr[2][4], vsv[2][4];
    #pragma unroll
    for (int cf = 0; cf < 2; ++cf){
      #pragma unroll
      for (int r = 0; r < 4; ++r)
        ksr[cf][r] = __shfl(sc_cf[cf], l4 * 4 + r) * RS;   // kscale via shfl
      const float4 vs = *(const float4*)&vscale[cf * 16 + l4 * 4];
      vsv[cf][0] = vs.x; vsv[cf][1] = vs.y; vsv[cf][2] = vs.z; vsv[cf][3] = vs.w;
    }
    const bool need_mask = (s0 + KT > S_ - Qn);      // only the last tile
    float x[2][4]; float rm = -1e30f;
    #pragma unroll
    for (int cf = 0; cf < 2; ++cf)
      #pragma unroll
      for (int r = 0; r < 4; ++r){
        float xx = st[cf][r] * ksr[cf][r];
        if (need_mask && (s0 + cf * 16 + l4 * 4 + r > S_ - Qn + l15)) xx = -1e30f;
        x[cf][r] = xx; rm = fmaxf(rm, xx);
      }
    rm = fmaxf(rm, __shfl_xor(rm, 16));
    rm = fmaxf(rm, __shfl_xor(rm, 32));
    const float mn  = fmaxf(m_i, rm);
    const float fac = __expf(m_i - mn);
    m_i = mn;
    float p[2][4]; float rs = 0.f;
    #pragma unroll
    for (int cf = 0; cf < 2; ++cf)
      #pragma unroll
      for (int r = 0; r < 4; ++r){
        p[cf][r] = __expf(x[cf][r] - mn);
        rs += p[cf][r];
      }
    rs += __shfl_xor(rs, 16);
    rs += __shfl_xor(rs, 32);
    l_i = l_i * fac + rs;

    // P~ = bf16(p * vscale[tok]) packed as u32 pairs, then 8-shfl transpose
    u32 pk0[2], pk1[2];
    #pragma unroll
    for (int rp = 0; rp < 2; ++rp){
      pk0[rp] = (u32)f2bf(p[0][2*rp] * vsv[0][2*rp]) | ((u32)f2bf(p[0][2*rp+1] * vsv[0][2*rp+1]) << 16);
      pk1[rp] = (u32)f2bf(p[1][2*rp] * vsv[1][2*rp]) | ((u32)f2bf(p[1][2*rp+1] * vsv[1][2*rp+1]) << 16);
    }
    const int s0L = ((l4 & 1) * 2) * 16 + l15;
    const int s1L = s0L + 16;
    const u32 a00 = __shfl((int)pk0[0], s0L), a01 = __shfl((int)pk0[1], s0L);
    const u32 a02 = __shfl((int)pk0[0], s1L), a03 = __shfl((int)pk0[1], s1L);
    const u32 a10 = __shfl((int)pk1[0], s0L), a11 = __shfl((int)pk1[1], s0L);
    const u32 a12 = __shfl((int)pk1[0], s1L), a13 = __shfl((int)pk1[1], s1L);
    const bool hi = (l4 >= 2);
    union { uint4 u; short8 s; } pfu;
    pfu.u = make_uint4(hi ? a10 : a00, hi ? a11 : a01,
                       hi ? a12 : a02, hi ? a13 : a03);
    const short8 pf = pfu.s;

    f32x4 facv;
    #pragma unroll
    for (int r = 0; r < 4; ++r) facv[r] = __shfl(fac, l4 * 4 + r);
    #pragma unroll
    for (int df = 0; df < 8; ++df) acc_o[df] *= facv;

    // ---- PV via MFMA: A = P~ (in-register), B = V^T tile ----
    __builtin_amdgcn_s_setprio(1);
    #pragma unroll
    for (int df = 0; df < 8; ++df){
      const int d = df * 16 + l15;
      const short8 vf = *(const short8*)&vt[d * VTS + l4 * 8];
      acc_o[df] = __builtin_amdgcn_mfma_f32_16x16x32_bf16(pf, vf, acc_o[df], 0, 0, 0);
    }
    __builtin_amdgcn_s_setprio(0);
    // no end barrier: next iter's gll targets raw[buf^1]; raw[buf] re-use is
    // gated by the next iteration's bar1 (all waves past this tile's reads).
  }

  asm volatile("s_waitcnt vmcnt(0)" ::: "memory");     // drain dangling prefetch
  __builtin_amdgcn_sched_barrier(0);

  // ---- write partials (unnormalized O, m, l) ----
  {
    const size_t base = (((size_t)b * KVH_ + kvh) * (size_t)NCHUNK + chunk) * ROWS;
    #pragma unroll
    for (int r = 0; r < 4; ++r){
      const int qrow = (w << 4) + (l4 << 2) + r;
      #pragma unroll
      for (int df = 0; df < 8; ++df)
        part_o[(base + qrow) * D_ + df * 16 + l15] = acc_o[df][r];
    }
    if (l4 == 0){                              // lanes 0..15 hold qi=l15 state
      part_ml[(base + (w << 4) + l15) * 2 + 0] = m_i;
      part_ml[(base + (w << 4) + l15) * 2 + 1] = l_i;
    }
  }
}

__global__ void attn_reduce(const float* __restrict__ part_o, const float* __restrict__ part_ml,
                            float* __restrict__ out)
{
  const int row = blockIdx.x;   // 0..63  (= g*16 + qi)
  const int kvh = blockIdx.y;
  const int b   = blockIdx.z;
  const int d   = threadIdx.x;  // 0..127
  const size_t base = ((size_t)b * KVH_ + kvh) * (size_t)NCHUNK;

  float M = -1e30f;
  for (int c = 0; c < NCHUNK; ++c)
    M = fmaxf(M, part_ml[((base + c) * ROWS + row) * 2 + 0]);
  float acc = 0.f, lt = 0.f;
  #pragma unroll
  for (int c = 0; c < NCHUNK; ++c){
    const float m = part_ml[((base + c) * ROWS + row) * 2 + 0];
    const float l = part_ml[((base + c) * ROWS + row) * 2 + 1];
    const float w = __expf(m - M);
    lt += w * l;
    acc += w * part_o[((base + c) * ROWS + row) * D_ + d];
  }
  const int g = row >> 4, qi = row & 15;
  out[(((size_t)b * Qn + qi) * Hh + kvh * G_ + g) * (size_t)D_ + d] = acc / lt;
}

extern "C" void kernel_launch(void* const* d_in, const int* in_sizes, int n_in,
                              void* d_out, int out_size, void* d_ws, size_t ws_size,
                              hipStream_t stream)
{
  const float* q = (const float*)d_in[0];
  const float* k = (const float*)d_in[1];
  const float* v = (const float*)d_in[2];
  // d_in[3] = block_table: identity permutation round-trip; ECC encode/decode
  // with no injected errors is the identity on the nibble -> fake-quant only.
  float* out = (float*)d_out;

  // part_o: B*KVH*NCHUNK*ROWS*D floats = 16.8 MB (ws verified >= 68 MB).
  float* part_o  = (float*)d_ws;
  float* part_ml = part_o + (size_t)B_ * KVH_ * NCHUNK * ROWS * D_;

  attn_partial<<<dim3(NCHUNK, KVH_, B_), THREADS, 0, stream>>>(q, k, v, part_o, part_ml);
  attn_reduce<<<dim3(ROWS, KVH_, B_), 128, 0, stream>>>(part_o, part_ml, out);
}

// Round 10
// 64.288 us; speedup vs baseline: 2.1555x; 1.2371x over previous
//
#include <hip/hip_runtime.h>
#include <hip/hip_bf16.h>

// Problem constants
#define B_    8
#define Qn    16
#define S_    4096
#define Hh    32
#define KVH_  8
#define D_    128
#define G_    4
#define ROWS  64          // G_*Qn score rows per (b,kvh)
#define KT    32          // tokens per inner tile
#define NT_TOT (S_ / KT)  // 128 tiles across the sequence
#define NCHUNK 12         // 768 blocks = 256 CU x 3 resident (LDS 50.5 KB)
#define THREADS 256
#define VTS   40          // vt row stride (shorts): 80B, 16B-aligned reads

typedef unsigned int u32;
typedef unsigned short u16;
typedef __attribute__((ext_vector_type(8))) short short8;   // 8 bf16 (4 VGPRs)
typedef __attribute__((ext_vector_type(4))) float f32x4;    // MFMA C/D

__device__ __forceinline__ u16 f2bf(float f){
  union{float f; u32 u;} t; t.f = f; u32 u = t.u;
  return (u16)((u + 0x7fffu + ((u >> 16) & 1u)) >> 16);   // RNE
}
__device__ __forceinline__ float bf2f(u16 h){
  union{u32 x; float f;} t; t.x = ((u32)h) << 16; return t.f;
}
// Quantize to signed nibble value held as bf16 (ints in [-7,7] exact, see R2).
__device__ __forceinline__ u16 qnib(float x, float inv){
  union{float f; u32 u;} t; t.f = rintf(x * inv);
  return (u16)(t.u >> 16);
}

// Async global->LDS DMA: no result register, tracked by vmcnt, NOT drained by
// raw s_barrier. LDS dest = wave-uniform base + lane*16 (linear).
__device__ __forceinline__ void gll16(const float* g, const float* lds){
  __builtin_amdgcn_global_load_lds((const __attribute__((address_space(1))) void*)g,
                                   (__attribute__((address_space(3))) void*)lds,
                                   16, 0, 0);
}

// attn_partial: grid (NCHUNK, KVH_, B_) x 256 threads, 3 blocks/CU.
// Per iter: [vmcnt(0); bar1] -> block-wide quant rawK->kn, rawV->vt
//           [lgkmcnt(0); bar2] -> issue gll(t+1) into the SAME raw buffers
//           (all raw reads completed block-wide at bar2) -> QK/softmax/PV.
// t+1's DMA is in flight across the whole compute phase (counted-vmcnt, T3/T4);
// with 3 blocks/CU the memory pipe stays busy while any block computes.
__global__ __launch_bounds__(THREADS)
__attribute__((amdgpu_waves_per_eu(3)))
void attn_partial(const float* __restrict__ q, const float* __restrict__ k,
                  const float* __restrict__ v, float* __restrict__ part_o,
                  float* __restrict__ part_ml)
{
  __shared__ float rawK[KT * D_];   // 16 KB raw f32 (single-buffered)
  __shared__ float rawV[KT * D_];   // 16 KB
  __shared__ u16   kn[KT * D_];     // 8 KB quantized K, granule-swizzled
  __shared__ u16   vt[D_ * VTS];    // 10 KB quantized V^T, padded rows
  __shared__ float kscale[KT];
  __shared__ float vscale[KT];

  const int chunk = blockIdx.x;
  const int kvh   = blockIdx.y;
  const int b     = blockIdx.z;
  const int tid   = threadIdx.x;
  const int lane  = tid & 63;
  const int w     = tid >> 6;                  // wave id == head group g
  const int l15   = lane & 15;
  const int l4    = lane >> 4;                 // 0..3
  const int t0    = (chunk * NT_TOT) / NCHUNK;
  const int t1    = ((chunk + 1) * NT_TOT) / NCHUNK;
  const float RS = 0.08838834764831844f;       // 1/sqrt(128)

  // quant-phase assignment: thread <-> token lt, dims {qd4 + m*32 ..+3}
  const int lt  = tid >> 3;                    // token 0..31
  const int qd4 = (tid & 7) * 4;

  // ---- Q fragments (hi/lo bf16 split) straight into registers ----
  short8 qhi[4], qlo[4];
  {
    const int h = kvh * G_ + w;
    const float* qp = q + (((size_t)(b * Qn + l15) * Hh) + h) * (size_t)D_ + (l4 * 8);
    #pragma unroll
    for (int kc = 0; kc < 4; ++kc){
      const float4 a = *(const float4*)(qp + kc * 32);
      const float4 c = *(const float4*)(qp + kc * 32 + 4);
      const float fv[8] = {a.x, a.y, a.z, a.w, c.x, c.y, c.z, c.w};
      #pragma unroll
      for (int i = 0; i < 8; ++i){
        const u16 hi = f2bf(fv[i]);
        qhi[kc][i] = (short)hi;
        qlo[kc][i] = (short)f2bf(fv[i] - bf2f(hi));
      }
    }
  }

  float m_i = -1e30f, l_i = 0.f;               // per-lane, qi = l15 view
  f32x4 acc_o[8];                              // O: col d = df*16+l15, row qi = l4*4+reg
  #pragma unroll
  for (int df = 0; df < 8; ++df) acc_o[df] = (f32x4)0.f;

  // gll mapping (linear): issue j covers granules (w*4+j)*64 + lane
  const int lhi = lane >> 5, cp = lane & 31;
  int goff[4];
  #pragma unroll
  for (int j = 0; j < 4; ++j){
    const int tokp = (w * 4 + j) * 2 + lhi;
    goff[j] = tokp * (KVH_ * D_) + (cp << 2);
  }
  const size_t tb0 = ((size_t)b * S_) * KVH_ * D_ + (size_t)kvh * D_;

  // ---- prologue: issue async staging of tile t0 ----
  {
    const size_t base = tb0 + (size_t)(t0 * KT) * KVH_ * D_;
    #pragma unroll
    for (int j = 0; j < 4; ++j) gll16(k + base + goff[j], &rawK[(w * 4 + j) * 256]);
    #pragma unroll
    for (int j = 0; j < 4; ++j) gll16(v + base + goff[j], &rawV[(w * 4 + j) * 256]);
  }

  for (int t = t0; t < t1; ++t){
    const int s0 = t * KT;

    asm volatile("s_waitcnt vmcnt(0)" ::: "memory");   // tile t landed (this wave)
    __builtin_amdgcn_sched_barrier(0);
    __builtin_amdgcn_s_barrier();                      // all waves' tile visible
    __builtin_amdgcn_sched_barrier(0);

    // ---- block-wide K quant: rawK -> kn (R5-verified layout) ----
    {
      float4 r4[4]; float am = 0.f;
      #pragma unroll
      for (int m = 0; m < 4; ++m){
        r4[m] = *(const float4*)&rawK[lt * D_ + qd4 + m * 32];
        am = fmaxf(am, fmaxf(fmaxf(fabsf(r4[m].x), fabsf(r4[m].y)),
                             fmaxf(fabsf(r4[m].z), fabsf(r4[m].w))));
      }
      am = fmaxf(am, __shfl_xor(am, 1));
      am = fmaxf(am, __shfl_xor(am, 2));
      am = fmaxf(am, __shfl_xor(am, 4));
      const float sc = fmaxf(am * (1.f / 7.f), 1e-8f);
      if ((tid & 7) == 0) kscale[lt] = sc;
      const float inv = 1.f / sc;
      #pragma unroll
      for (int m = 0; m < 4; ++m){
        const int d0 = qd4 + m * 32;
        const int idx = lt * D_ + ((((d0 >> 3) ^ (lt & 7)) << 3) | (d0 & 7));
        *(ushort4*)&kn[idx] = make_ushort4(qnib(r4[m].x, inv), qnib(r4[m].y, inv),
                                           qnib(r4[m].z, inv), qnib(r4[m].w, inv));
      }
    }
    // ---- block-wide V quant: rawV -> vt (transposed, padded rows) ----
    {
      float4 r4[4]; float am = 0.f;
      #pragma unroll
      for (int m = 0; m < 4; ++m){
        r4[m] = *(const float4*)&rawV[lt * D_ + qd4 + m * 32];
        am = fmaxf(am, fmaxf(fmaxf(fabsf(r4[m].x), fabsf(r4[m].y)),
                             fmaxf(fabsf(r4[m].z), fabsf(r4[m].w))));
      }
      am = fmaxf(am, __shfl_xor(am, 1));
      am = fmaxf(am, __shfl_xor(am, 2));
      am = fmaxf(am, __shfl_xor(am, 4));
      const float sc = fmaxf(am * (1.f / 7.f), 1e-8f);
      if ((tid & 7) == 0) vscale[lt] = sc;
      const float inv = 1.f / sc;
      #pragma unroll
      for (int m = 0; m < 4; ++m){
        const int d0 = qd4 + m * 32;
        vt[(d0 + 0) * VTS + lt] = qnib(r4[m].x, inv);
        vt[(d0 + 1) * VTS + lt] = qnib(r4[m].y, inv);
        vt[(d0 + 2) * VTS + lt] = qnib(r4[m].z, inv);
        vt[(d0 + 3) * VTS + lt] = qnib(r4[m].w, inv);
      }
    }
    asm volatile("s_waitcnt lgkmcnt(0)" ::: "memory"); // kn/vt/scales written
    __builtin_amdgcn_sched_barrier(0);
    __builtin_amdgcn_s_barrier();                      // raw fully consumed
    __builtin_amdgcn_sched_barrier(0);

    // ---- issue gll(t+1) into the same raw buffers; flies across compute ----
    {
      const int sn = (s0 + KT <= S_ - KT) ? (s0 + KT) : (S_ - KT);
      const size_t base = tb0 + (size_t)sn * KVH_ * D_;
      #pragma unroll
      for (int j = 0; j < 4; ++j) gll16(k + base + goff[j], &rawK[(w * 4 + j) * 256]);
      #pragma unroll
      for (int j = 0; j < 4; ++j) gll16(v + base + goff[j], &rawV[(w * 4 + j) * 256]);
    }

    // ---- QK^T (swapped): st[cf] C[tok=l4*4+r+16cf][qi=l15] ----
    f32x4 st[2];
    st[0] = (f32x4)0.f; st[1] = (f32x4)0.f;
    __builtin_amdgcn_s_setprio(1);
    #pragma unroll
    for (int kc = 0; kc < 4; ++kc){
      #pragma unroll
      for (int cf = 0; cf < 2; ++cf){
        const int tok = cf * 16 + l15;
        const int gr  = kc * 4 + l4;           // d-granule 0..15
        const short8 kf = *(const short8*)&kn[tok * D_ + ((gr ^ (tok & 7)) << 3)];
        st[cf] = __builtin_amdgcn_mfma_f32_16x16x32_bf16(kf, qhi[kc], st[cf], 0, 0, 0);
        st[cf] = __builtin_amdgcn_mfma_f32_16x16x32_bf16(kf, qlo[kc], st[cf], 0, 0, 0);
      }
    }
    __builtin_amdgcn_s_setprio(0);

    // ---- online softmax in [tok][qi] layout (R7-verified) ----
    float ksr[2][4], vsv[2][4];
    #pragma unroll
    for (int cf = 0; cf < 2; ++cf){
      const float4 ks = *(const float4*)&kscale[cf * 16 + l4 * 4];
      const float4 vs = *(const float4*)&vscale[cf * 16 + l4 * 4];
      ksr[cf][0] = ks.x * RS; ksr[cf][1] = ks.y * RS;
      ksr[cf][2] = ks.z * RS; ksr[cf][3] = ks.w * RS;
      vsv[cf][0] = vs.x; vsv[cf][1] = vs.y; vsv[cf][2] = vs.z; vsv[cf][3] = vs.w;
    }
    const bool need_mask = (s0 + KT > S_ - Qn);      // only the last tile
    float x[2][4]; float rm = -1e30f;
    #pragma unroll
    for (int cf = 0; cf < 2; ++cf)
      #pragma unroll
      for (int r = 0; r < 4; ++r){
        float xx = st[cf][r] * ksr[cf][r];
        if (need_mask && (s0 + cf * 16 + l4 * 4 + r > S_ - Qn + l15)) xx = -1e30f;
        x[cf][r] = xx; rm = fmaxf(rm, xx);
      }
    rm = fmaxf(rm, __shfl_xor(rm, 16));
    rm = fmaxf(rm, __shfl_xor(rm, 32));
    const float mn  = fmaxf(m_i, rm);
    const float fac = __expf(m_i - mn);
    m_i = mn;
    float p[2][4]; float rs = 0.f;
    #pragma unroll
    for (int cf = 0; cf < 2; ++cf)
      #pragma unroll
      for (int r = 0; r < 4; ++r){
        p[cf][r] = __expf(x[cf][r] - mn);
        rs += p[cf][r];
      }
    rs += __shfl_xor(rs, 16);
    rs += __shfl_xor(rs, 32);
    l_i = l_i * fac + rs;

    // P~ = bf16(p * vscale[tok]) packed, then 8-shfl transpose to PV A-frag
    u32 pk0[2], pk1[2];
    #pragma unroll
    for (int rp = 0; rp < 2; ++rp){
      pk0[rp] = (u32)f2bf(p[0][2*rp] * vsv[0][2*rp]) | ((u32)f2bf(p[0][2*rp+1] * vsv[0][2*rp+1]) << 16);
      pk1[rp] = (u32)f2bf(p[1][2*rp] * vsv[1][2*rp]) | ((u32)f2bf(p[1][2*rp+1] * vsv[1][2*rp+1]) << 16);
    }
    const int s0L = ((l4 & 1) * 2) * 16 + l15;
    const int s1L = s0L + 16;
    const u32 a00 = __shfl((int)pk0[0], s0L), a01 = __shfl((int)pk0[1], s0L);
    const u32 a02 = __shfl((int)pk0[0], s1L), a03 = __shfl((int)pk0[1], s1L);
    const u32 a10 = __shfl((int)pk1[0], s0L), a11 = __shfl((int)pk1[1], s0L);
    const u32 a12 = __shfl((int)pk1[0], s1L), a13 = __shfl((int)pk1[1], s1L);
    const bool hi = (l4 >= 2);
    union { uint4 u; short8 s; } pfu;
    pfu.u = make_uint4(hi ? a10 : a00, hi ? a11 : a01,
                       hi ? a12 : a02, hi ? a13 : a03);
    const short8 pf = pfu.s;

    f32x4 facv;
    #pragma unroll
    for (int r = 0; r < 4; ++r) facv[r] = __shfl(fac, l4 * 4 + r);
    #pragma unroll
    for (int df = 0; df < 8; ++df) acc_o[df] *= facv;

    // ---- PV via MFMA: A = P~ (in-register), B = V^T tile ----
    __builtin_amdgcn_s_setprio(1);
    #pragma unroll
    for (int df = 0; df < 8; ++df){
      const int d = df * 16 + l15;
      const short8 vf = *(const short8*)&vt[d * VTS + l4 * 8];
      acc_o[df] = __builtin_amdgcn_mfma_f32_16x16x32_bf16(pf, vf, acc_o[df], 0, 0, 0);
    }
    __builtin_amdgcn_s_setprio(0);
    // no end barrier: vt/kn re-writes are gated by next iter's bar1.
  }

  asm volatile("s_waitcnt vmcnt(0)" ::: "memory");     // drain dangling prefetch
  __builtin_amdgcn_sched_barrier(0);

  // ---- write partials (unnormalized O, m, l) ----
  {
    const size_t base = (((size_t)b * KVH_ + kvh) * (size_t)NCHUNK + chunk) * ROWS;
    #pragma unroll
    for (int r = 0; r < 4; ++r){
      const int qrow = (w << 4) + (l4 << 2) + r;
      #pragma unroll
      for (int df = 0; df < 8; ++df)
        part_o[(base + qrow) * D_ + df * 16 + l15] = acc_o[df][r];
    }
    if (l4 == 0){                              // lanes 0..15 hold qi=l15 state
      part_ml[(base + (w << 4) + l15) * 2 + 0] = m_i;
      part_ml[(base + (w << 4) + l15) * 2 + 1] = l_i;
    }
  }
}

__global__ void attn_reduce(const float* __restrict__ part_o, const float* __restrict__ part_ml,
                            float* __restrict__ out)
{
  const int row = blockIdx.x;   // 0..63  (= g*16 + qi)
  const int kvh = blockIdx.y;
  const int b   = blockIdx.z;
  const int d   = threadIdx.x;  // 0..127
  const size_t base = ((size_t)b * KVH_ + kvh) * (size_t)NCHUNK;

  float M = -1e30f;
  for (int c = 0; c < NCHUNK; ++c)
    M = fmaxf(M, part_ml[((base + c) * ROWS + row) * 2 + 0]);
  float acc = 0.f, lt = 0.f;
  #pragma unroll
  for (int c = 0; c < NCHUNK; ++c){
    const float m = part_ml[((base + c) * ROWS + row) * 2 + 0];
    const float l = part_ml[((base + c) * ROWS + row) * 2 + 1];
    const float w = __expf(m - M);
    lt += w * l;
    acc += w * part_o[((base + c) * ROWS + row) * D_ + d];
  }
  const int g = row >> 4, qi = row & 15;
  out[(((size_t)b * Qn + qi) * Hh + kvh * G_ + g) * (size_t)D_ + d] = acc / lt;
}

extern "C" void kernel_launch(void* const* d_in, const int* in_sizes, int n_in,
                              void* d_out, int out_size, void* d_ws, size_t ws_size,
                              hipStream_t stream)
{
  const float* q = (const float*)d_in[0];
  const float* k = (const float*)d_in[1];
  const float* v = (const float*)d_in[2];
  // d_in[3] = block_table: identity permutation round-trip; ECC encode/decode
  // with no injected errors is the identity on the nibble -> fake-quant only.
  float* out = (float*)d_out;

  // part_o: B*KVH*NCHUNK*ROWS*D floats = 25.2 MB (fits d_ws as in R3-R8).
  float* part_o  = (float*)d_ws;
  float* part_ml = part_o + (size_t)B_ * KVH_ * NCHUNK * ROWS * D_;

  attn_partial<<<dim3(NCHUNK, KVH_, B_), THREADS, 0, stream>>>(q, k, v, part_o, part_ml);
  attn_reduce<<<dim3(ROWS, KVH_, B_), 128, 0, stream>>>(part_o, part_ml, out);
}